// Round 10
// baseline (91.870 us; speedup 1.0000x reference)
//
#include <hip/hip_runtime.h>

// TimeNormalization: EMA scan over time + normalization.
//   s_t = 0.1*[x, x^2] + 0.9*s_{t-1}   (per (b,f), scan over t)
//   x_norm = (x - m) / sqrt(v - m^2 + 1e-3)
// Outputs concatenated: x_norm [B,T,F] then final_state [2,B,F].
//
// Standing model (R1-R8): bench time == total L2-miss bytes / ~6.0 TB/s;
// saturation needs >=1024 waves. R6 halo = 295 MB = 49.5 us. This round
// removes the halo (x read from HBM exactly once, 267 MB):
//   - 0.9^512 ~ 3.7e-24: a chunk's zero-init local final state equals its
//     true final state to f32 rounding (correction absorbed) -> chunk
//     dependency depth is 1, no chain.
//   - only rows [0,128) of a chunk need the predecessor state (0.9^129).
// Phase 1: local scan, stash first 128 x-rows in LDS, write rows
// [128,512), publish local final as ONE packed 64-bit agent atomic
// (single-copy atomic -> no partial (m,v) visibility, the R9 NaN bug).
// Handoff buffer is sentinel-filled (0xFF = NaN|NaN) by a stream-ordered
// hipMemsetAsync each call; consumers spin until word != sentinel.
// Phase 2: exact incoming state, replay stashed rows, write rows [0,128).
// Deadlock-free: 512 blocks x 64KB LDS = exactly 2/CU x 256 CU -> whole
// grid co-resident; chunk-outermost block IDs as belt-and-braces.

namespace {
constexpr int Bc = 16, Tc = 4096, Fc = 512;
constexpr int CL = 512;            // chunk length
constexpr int KH = 128;            // rows needing exact incoming state
constexpr int NCHUNK = Tc / CL;    // 8
constexpr int LANES = 128;         // threads/block (f-quarter)
constexpr float ALPHA = 0.1f;
constexpr float OMA = 0.9f;
constexpr float EPS = 1e-3f;
typedef unsigned long long u64;
constexpr u64 SENTINEL = ~0ull;    // memset 0xFF pattern; packed finite (m,v) can never equal it
}

__global__ __launch_bounds__(LANES) void tn_chain(const float* __restrict__ x,
                                                  const float* __restrict__ state,
                                                  float* __restrict__ out,
                                                  u64* __restrict__ hand) {
    __shared__ float stash[KH * LANES];   // 64 KB, thread-private columns (no barrier needed)

    // blockIdx = chunk*64 + b*4 + fq  (chunk outermost: wait only on lower IDs)
    const int bid = blockIdx.x;
    const int chunk = bid >> 6;
    const int inner = bid & 63;
    const int b = inner >> 2;
    const int fq = inner & 3;
    const int f = fq * LANES + threadIdx.x;

    const size_t base = ((size_t)b * Tc + chunk * CL) * Fc + f;
    const float* xp = x + base;
    float* op = out + base;

    // ---- Phase 1: local scan (chunk 0 exact init, others zero-init) ----
    const bool c0 = (chunk == 0);
    float s_m, s_v;
    if (c0) {
        s_m = state[b * Fc + f];
        s_v = state[Bc * Fc + b * Fc + f];
    } else {
        s_m = 0.f;
        s_v = 0.f;
    }

#pragma unroll 16
    for (int i = 0; i < KH; ++i) {        // stash rows [0,KH); chunk 0 writes out too
        float xv = xp[(size_t)i * Fc];
        stash[i * LANES + threadIdx.x] = xv;
        float px = ALPHA * xv;
        s_m = fmaf(OMA, s_m, px);
        s_v = fmaf(OMA, s_v, px * xv);
        if (c0) {
            float var = fmaf(-s_m, s_m, s_v);
            __builtin_nontemporal_store((xv - s_m) * rsqrtf(var + EPS),
                                        &op[(size_t)i * Fc]);
        }
    }
#pragma unroll 16
    for (int i = KH; i < CL; ++i) {       // rows [KH,CL): trunc err <= 0.9^129 ~ 1.2e-6
        float xv = xp[(size_t)i * Fc];
        float px = ALPHA * xv;
        s_m = fmaf(OMA, s_m, px);
        s_v = fmaf(OMA, s_v, px * xv);
        float var = fmaf(-s_m, s_m, s_v);
        __builtin_nontemporal_store((xv - s_m) * rsqrtf(var + EPS),
                                    &op[(size_t)i * Fc]);
    }

    if (chunk == NCHUNK - 1) {
        // local final == true final (0.9^512 correction absorbed by f32 rounding)
        const size_t so = (size_t)Bc * Tc * Fc;
        out[so + (size_t)b * Fc + f] = s_m;
        out[so + (size_t)Bc * Fc + (size_t)b * Fc + f] = s_v;
    } else {
        // publish local final as ONE 64-bit word: atomic -> all-or-nothing
        u64 w = ((u64)__float_as_uint(s_v) << 32) | (u64)__float_as_uint(s_m);
        __hip_atomic_store(&hand[(size_t)(b * NCHUNK + chunk) * Fc + f], w,
                           __ATOMIC_RELAXED, __HIP_MEMORY_SCOPE_AGENT);
    }

    // ---- Phase 2 (chunks > 0): exact predecessor state, replay stash ----
    if (!c0) {
        const size_t pidx = (size_t)(b * NCHUNK + chunk - 1) * Fc + f;
        u64 w = __hip_atomic_load(&hand[pidx], __ATOMIC_RELAXED,
                                  __HIP_MEMORY_SCOPE_AGENT);
        while (w == SENTINEL) {
            __builtin_amdgcn_s_sleep(1);
            w = __hip_atomic_load(&hand[pidx], __ATOMIC_RELAXED,
                                  __HIP_MEMORY_SCOPE_AGENT);
        }
        float m = __uint_as_float((unsigned)w);
        float v = __uint_as_float((unsigned)(w >> 32));
#pragma unroll 16
        for (int i = 0; i < KH; ++i) {    // rows [0,KH) now exact; x from LDS
            float xv = stash[i * LANES + threadIdx.x];
            float px = ALPHA * xv;
            m = fmaf(OMA, m, px);
            v = fmaf(OMA, v, px * xv);
            float var = fmaf(-m, m, v);
            __builtin_nontemporal_store((xv - m) * rsqrtf(var + EPS),
                                        &op[(size_t)i * Fc]);
        }
    }
}

// ---- Fallback (R6 halo kernel, 49.5 us) if ws_size is too small ----
__global__ __launch_bounds__(256) void tn_halo(const float* __restrict__ x,
                                               const float* __restrict__ state,
                                               float* __restrict__ out) {
    const int bid = blockIdx.x;            // grid = B * NCHUNK * 2 = 256
    const int fh = bid & 1;
    const int chunk = (bid >> 1) & (NCHUNK - 1);
    const int b = bid >> 4;
    const int f = fh * 256 + threadIdx.x;
    const int t0 = chunk * CL;

    const size_t base = ((size_t)b * Tc + t0) * Fc + f;
    const float* xp = x + base;

    float s_m, s_v;
    if (chunk == 0) {
        s_m = state[b * Fc + f];
        s_v = state[Bc * Fc + b * Fc + f];
    } else {
        s_m = 0.f;
        s_v = 0.f;
        const float* wp = xp - (size_t)KH * Fc;
#pragma unroll 16
        for (int i = 0; i < KH; ++i) {
            float xv = wp[(size_t)i * Fc];
            float px = ALPHA * xv;
            s_m = fmaf(OMA, s_m, px);
            s_v = fmaf(OMA, s_v, px * xv);
        }
    }

    float* op = out + base;
#pragma unroll 16
    for (int i = 0; i < CL; ++i) {
        float xv = xp[(size_t)i * Fc];
        float px = ALPHA * xv;
        s_m = fmaf(OMA, s_m, px);
        s_v = fmaf(OMA, s_v, px * xv);
        float var = fmaf(-s_m, s_m, s_v);
        __builtin_nontemporal_store((xv - s_m) * rsqrtf(var + EPS),
                                    &op[(size_t)i * Fc]);
    }

    if (chunk == NCHUNK - 1) {
        const size_t so = (size_t)Bc * Tc * Fc;
        out[so + (size_t)b * Fc + f] = s_m;
        out[so + (size_t)Bc * Fc + (size_t)b * Fc + f] = s_v;
    }
}

extern "C" void kernel_launch(void* const* d_in, const int* in_sizes, int n_in,
                              void* d_out, int out_size, void* d_ws, size_t ws_size,
                              hipStream_t stream) {
    const float* x = (const float*)d_in[0];      // [B,T,F] f32
    const float* st = (const float*)d_in[1];     // [2,B,F] f32
    float* out = (float*)d_out;                  // x_norm + final_state

    const size_t hand_bytes = (size_t)Bc * NCHUNK * Fc * sizeof(u64);  // 512 KB
    if (ws_size >= hand_bytes) {
        u64* hand = (u64*)d_ws;
        // sentinel-fill the handoff buffer (stream-ordered, graph-capturable)
        hipMemsetAsync(d_ws, 0xFF, hand_bytes, stream);
        tn_chain<<<dim3(NCHUNK * Bc * 4), dim3(LANES), 0, stream>>>(x, st, out, hand);
    } else {
        tn_halo<<<dim3(Bc * NCHUNK * 2), dim3(256), 0, stream>>>(x, st, out);
    }
}

// Round 11
// 53.430 us; speedup vs baseline: 1.7194x; 1.7194x over previous
//
#include <hip/hip_runtime.h>

// TimeNormalization: EMA scan over time + normalization.
//   s_t = 0.1*[x, x^2] + 0.9*s_{t-1}   (per (b,f), scan over t)
//   x_norm = (x - m) / sqrt(v - m^2 + 1e-3)
// Outputs concatenated: x_norm [B,T,F] then final_state [2,B,F].
//
// Final structure (R1-R10 evidence):
//  - bench time == total L2-miss bytes / fabric BW in every config.
//  - fabric BW: 4.4 TB/s @2 waves/CU, ~6.0 @4, ~6.3 @>=8 (R2/R4/R8).
//  - halo warmup (KH=128, 0.9^128 ~ 1.4e-6) costs 29 MB; removing it via
//    2-phase handoff/grid-sync (R7/R10) costs +40 us -> halo wins.
//  - KH accuracy-pinned: KH=96 would grow absmax ~29x past threshold.
// This round: R6's traffic (CL=512, amp 1.25, 295 MB) at 8 waves/CU
// (1024 blocks x 128 thr, f-quarters) to reach the 6.3 TB/s ceiling.

namespace {
constexpr int Bc = 16, Tc = 4096, Fc = 512;
constexpr int CL = 512;          // chunk length (amp = 1 + 128/512 = 1.25)
constexpr int KH = 128;          // halo (accuracy-critical, don't shrink)
constexpr int NCHUNK = Tc / CL;  // 8
constexpr int LANES = 128;       // f-quarter per block
constexpr float ALPHA = 0.1f;
constexpr float OMA = 0.9f;
constexpr float EPS = 1e-3f;
}

__global__ __launch_bounds__(LANES) void tn_kernel(const float* __restrict__ x,
                                                   const float* __restrict__ state,
                                                   float* __restrict__ out) {
    // grid = B * NCHUNK * 4 = 1024 blocks (2048 waves = 8 waves/CU)
    const int bid = blockIdx.x;
    const int fq = bid & 3;                // f-quarter (fastest)
    const int chunk = (bid >> 2) & (NCHUNK - 1);
    const int b = bid >> 5;
    const int f = fq * LANES + threadIdx.x;  // coalesced feature index
    const int t0 = chunk * CL;

    const size_t base = ((size_t)b * Tc + t0) * Fc + f;
    const float* xp = x + base;

    float s_m, s_v;
    if (chunk == 0) {
        // exact initial state: state[0,b,f] (mean), state[1,b,f] (mean-square)
        s_m = state[b * Fc + f];
        s_v = state[Bc * Fc + b * Fc + f];
    } else {
        // halo warmup; truncated history contributes <= 0.9^KH ~ 1.4e-6
        s_m = 0.f;
        s_v = 0.f;
        const float* wp = xp - (size_t)KH * Fc;
#pragma unroll 16
        for (int i = 0; i < KH; ++i) {
            float xv = wp[(size_t)i * Fc];
            float px = ALPHA * xv;
            s_m = fmaf(OMA, s_m, px);
            s_v = fmaf(OMA, s_v, px * xv);
        }
    }

    float* op = out + base;
#pragma unroll 16
    for (int i = 0; i < CL; ++i) {
        float xv = xp[(size_t)i * Fc];
        float px = ALPHA * xv;
        s_m = fmaf(OMA, s_m, px);
        s_v = fmaf(OMA, s_v, px * xv);
        float var = fmaf(-s_m, s_m, s_v);          // v - m^2
        float r = (xv - s_m) * rsqrtf(var + EPS);
        __builtin_nontemporal_store(r, &op[(size_t)i * Fc]);  // write-once stream
    }

    if (chunk == NCHUNK - 1) {
        // final_state [2,B,F] appended after x_norm
        const size_t so = (size_t)Bc * Tc * Fc;
        out[so + (size_t)b * Fc + f] = s_m;
        out[so + (size_t)Bc * Fc + (size_t)b * Fc + f] = s_v;
    }
}

extern "C" void kernel_launch(void* const* d_in, const int* in_sizes, int n_in,
                              void* d_out, int out_size, void* d_ws, size_t ws_size,
                              hipStream_t stream) {
    const float* x = (const float*)d_in[0];      // [B,T,F] f32
    const float* st = (const float*)d_in[1];     // [2,B,F] f32
    float* out = (float*)d_out;                  // x_norm + final_state

    dim3 grid(Bc * NCHUNK * 4);                  // 1024
    dim3 block(LANES);                           // 128
    tn_kernel<<<grid, block, 0, stream>>>(x, st, out);
}

// Round 12
// 50.319 us; speedup vs baseline: 1.8258x; 1.0618x over previous
//
#include <hip/hip_runtime.h>

// TimeNormalization: EMA scan over time + normalization.
//   s_t = 0.1*[x, x^2] + 0.9*s_{t-1}   (per (b,f), scan over t)
//   x_norm = (x - m) / sqrt(v - m^2 + 1e-3)
// Outputs concatenated: x_norm [B,T,F] then final_state [2,B,F].
//
// FINAL (R6 configuration — best of 11 rounds, 49.5 us):
//  - Chunked scan, CL=512, KH=128 halo warmup (0.9^128 ~ 1.4e-6; chunk 0
//    exact). Traffic = 134*(1+128/512) + 131 = 295 MB.
//  - bench time == total L2-miss bytes / ~6.0 TB/s in every config tested
//    (R1-R11); this kernel runs at 95% of the 6.29 TB/s copy ceiling.
//  - Closed alternatives: grid-sync dedup (R7, +81 us), flag-handoff
//    2-phase (R10, +42 us), CL=1024 @ low occupancy (R8, BW collapse),
//    8 waves/CU 128-thr blocks (R11, -8%), vec4 (R3, neutral),
//    sw-pipelining (R5, neutral). KH=128 accuracy-pinned (0.9^KH scaling:
//    KH=96 -> absmax ~0.44 > 0.0678 threshold).

namespace {
constexpr int Bc = 16, Tc = 4096, Fc = 512;
constexpr int CL = 512;          // chunk length (amp = 1 + 128/512 = 1.25)
constexpr int KH = 128;          // halo (accuracy-critical, don't shrink)
constexpr int NCHUNK = Tc / CL;  // 8
constexpr float ALPHA = 0.1f;
constexpr float OMA = 0.9f;
constexpr float EPS = 1e-3f;
}

__global__ __launch_bounds__(256) void tn_kernel(const float* __restrict__ x,
                                                 const float* __restrict__ state,
                                                 float* __restrict__ out) {
    // grid = B * NCHUNK * 2 = 256 blocks (1/CU), 256 threads each
    const int bid = blockIdx.x;
    const int fh = bid & 1;                // which half of F
    const int chunk = (bid >> 1) & (NCHUNK - 1);
    const int b = bid >> 4;                // 2*NCHUNK = 16
    const int f = fh * 256 + threadIdx.x;  // coalesced feature index
    const int t0 = chunk * CL;

    const size_t base = ((size_t)b * Tc + t0) * Fc + f;
    const float* xp = x + base;

    float s_m, s_v;
    if (chunk == 0) {
        // exact initial state: state[0,b,f] (mean), state[1,b,f] (mean-square)
        s_m = state[b * Fc + f];
        s_v = state[Bc * Fc + b * Fc + f];
    } else {
        // halo warmup; truncated history contributes <= 0.9^KH ~ 1.4e-6
        s_m = 0.f;
        s_v = 0.f;
        const float* wp = xp - (size_t)KH * Fc;
#pragma unroll 16
        for (int i = 0; i < KH; ++i) {
            float xv = wp[(size_t)i * Fc];
            float px = ALPHA * xv;
            s_m = fmaf(OMA, s_m, px);
            s_v = fmaf(OMA, s_v, px * xv);
        }
    }

    float* op = out + base;
#pragma unroll 16
    for (int i = 0; i < CL; ++i) {
        float xv = xp[(size_t)i * Fc];
        float px = ALPHA * xv;
        s_m = fmaf(OMA, s_m, px);
        s_v = fmaf(OMA, s_v, px * xv);
        float var = fmaf(-s_m, s_m, s_v);          // v - m^2
        float r = (xv - s_m) * rsqrtf(var + EPS);
        __builtin_nontemporal_store(r, &op[(size_t)i * Fc]);  // write-once stream
    }

    if (chunk == NCHUNK - 1) {
        // final_state [2,B,F] appended after x_norm
        const size_t so = (size_t)Bc * Tc * Fc;
        out[so + (size_t)b * Fc + f] = s_m;
        out[so + (size_t)Bc * Fc + (size_t)b * Fc + f] = s_v;
    }
}

extern "C" void kernel_launch(void* const* d_in, const int* in_sizes, int n_in,
                              void* d_out, int out_size, void* d_ws, size_t ws_size,
                              hipStream_t stream) {
    const float* x = (const float*)d_in[0];      // [B,T,F] f32
    const float* st = (const float*)d_in[1];     // [2,B,F] f32
    float* out = (float*)d_out;                  // x_norm + final_state

    dim3 grid(Bc * NCHUNK * 2);                  // 256
    dim3 block(256);
    tn_kernel<<<grid, block, 0, stream>>>(x, st, out);
}